// Round 2
// baseline (379.131 us; speedup 1.0000x reference)
//
#include <hip/hip_runtime.h>
#include <math.h>

// NeuralMMU: out[b] = pack26( (gelu(bits(addr) @ W1 + b1) @ W2 + b2)[:26] > 0.5 )
// bits 0..30 only (addresses < 2^31). Layer1 via 6-group LUT in LDS; layer2 via
// __constant__ W2 (s_load, SMEM pipe); fp64 rescue for logits within EPS of 0.5.
// Output dtype: int32 (harness reads int64-ref outputs as np.int32).

#define NROWS      224          // 64 (bits0-5, b1 folded) + 5*32 (5-bit groups)
#define LUT_STRIDE 132          // +4 floats pad: rows rotate over 8 bank-quads
#define LUT_FLOATS (NROWS * LUT_STRIDE)   // 29568 floats = 118272 B
#define FLAG_CAP   (1 << 18)
#define EPS_F      4e-4f

__device__ __align__(16) float g_lut[LUT_FLOATS];
__device__ int g_flagCnt;
__device__ int g_flags[FLAG_CAP];
__device__ int g_is64;

__constant__ float cW2[128 * 64];
__constant__ float cB2[64];

// ---------------- init: reset flag counter, detect int64-vs-int32 storage ----
__global__ void k_init(const unsigned int* __restrict__ va32, int nchk) {
    __shared__ unsigned int s_or;
    int tid = threadIdx.x;
    if (tid == 0) s_or = 0;
    __syncthreads();
    unsigned int acc = 0;
    // If input is int64 (little-endian, values < 2^31), every odd word is 0.
    for (int i = tid; i < nchk; i += blockDim.x) acc |= va32[2 * i + 1];
    if (acc) atomicOr(&s_or, acc);
    __syncthreads();
    if (tid == 0) {
        g_is64 = (s_or == 0) ? 1 : 0;
        g_flagCnt = 0;
    }
}

// ---------------- build LUT (fp64 accumulate, fp32 store) --------------------
__global__ void k_build(const float* __restrict__ W1, const float* __restrict__ b1) {
    int t = blockIdx.x * blockDim.x + threadIdx.x;   // 224*128 = 28672 threads
    if (t >= NROWS * 128) return;
    int row = t >> 7;
    int k   = t & 127;
    int m, bit0, nbits;
    double acc;
    if (row < 64) { m = row;            bit0 = 0;                     nbits = 6; acc = (double)b1[k]; }
    else          { int g = (row - 64) >> 5;
                    m = (row - 64) & 31; bit0 = 6 + 5 * g;            nbits = 5; acc = 0.0; }
    for (int i = 0; i < nbits; i++)
        if ((m >> i) & 1) acc += (double)W1[(bit0 + i) * 128 + k];
    g_lut[row * LUT_STRIDE + k] = (float)acc;
}

// ---------------- main fast path (fp32) --------------------------------------
__device__ __forceinline__ float gelu_f(float x) {
    return 0.5f * x * (1.0f + erff(x * 0.70710678118654752f));
}

__global__ __launch_bounds__(1024) void k_main(const unsigned int* __restrict__ va32,
                                               int* __restrict__ out, int n) {
    extern __shared__ float lut[];
    { // stage LUT into LDS (float4)
        const float4* src = (const float4*)g_lut;
        float4* dst = (float4*)lut;
        for (int i = threadIdx.x; i < LUT_FLOATS / 4; i += blockDim.x) dst[i] = src[i];
    }
    __syncthreads();

    int i = blockIdx.x * blockDim.x + threadIdx.x;
    if (i >= n) return;
    int is64 = g_is64;
    unsigned int addr = is64 ? va32[2 * i] : va32[i];

    const float* p0 = lut + (addr & 63u) * LUT_STRIDE;
    const float* p1 = lut + (64u  + ((addr >> 6)  & 31u)) * LUT_STRIDE;
    const float* p2 = lut + (96u  + ((addr >> 11) & 31u)) * LUT_STRIDE;
    const float* p3 = lut + (128u + ((addr >> 16) & 31u)) * LUT_STRIDE;
    const float* p4 = lut + (160u + ((addr >> 21) & 31u)) * LUT_STRIDE;
    const float* p5 = lut + (192u + ((addr >> 26) & 31u)) * LUT_STRIDE;

    float acc[26];
#pragma unroll
    for (int j = 0; j < 26; j++) acc[j] = 0.0f;

#pragma unroll 2
    for (int k = 0; k < 128; k += 4) {
        float4 a  = *(const float4*)(p0 + k);
        float4 t1 = *(const float4*)(p1 + k);
        float4 t2 = *(const float4*)(p2 + k);
        float4 t3 = *(const float4*)(p3 + k);
        float4 t4 = *(const float4*)(p4 + k);
        float4 t5 = *(const float4*)(p5 + k);
        a.x += t1.x; a.y += t1.y; a.z += t1.z; a.w += t1.w;
        a.x += t2.x; a.y += t2.y; a.z += t2.z; a.w += t2.w;
        a.x += t3.x; a.y += t3.y; a.z += t3.z; a.w += t3.w;
        a.x += t4.x; a.y += t4.y; a.z += t4.z; a.w += t4.w;
        a.x += t5.x; a.y += t5.y; a.z += t5.z; a.w += t5.w;
        float h0 = gelu_f(a.x), h1 = gelu_f(a.y), h2 = gelu_f(a.z), h3 = gelu_f(a.w);
#pragma unroll
        for (int j = 0; j < 26; j++) {
            // cW2 index is wave-uniform (k, j loop-invariant per iter) -> s_load
            acc[j] = fmaf(h0, cW2[(k + 0) * 64 + j], acc[j]);
            acc[j] = fmaf(h1, cW2[(k + 1) * 64 + j], acc[j]);
            acc[j] = fmaf(h2, cW2[(k + 2) * 64 + j], acc[j]);
            acc[j] = fmaf(h3, cW2[(k + 3) * 64 + j], acc[j]);
        }
    }

    unsigned int packed = 0, borderline = 0;
#pragma unroll
    for (int j = 0; j < 26; j++) {
        float thr = 0.5f - cB2[j];
        float d = acc[j] - thr;
        if (d > 0.0f) packed |= (1u << j);
        if (fabsf(d) < EPS_F) borderline = 1u;
    }
    out[i] = (int)packed;
    if (borderline) {
        int idx = atomicAdd(&g_flagCnt, 1);
        if (idx < FLAG_CAP) g_flags[idx] = i;
    }
}

// ---------------- rescue: exact fp64 recompute of flagged addresses ----------
__global__ void k_rescue(const unsigned int* __restrict__ va32,
                         const float* __restrict__ W1, const float* __restrict__ b1,
                         const float* __restrict__ W2, const float* __restrict__ b2,
                         int* __restrict__ out) {
    int gtid = blockIdx.x * blockDim.x + threadIdx.x;
    int lane = threadIdx.x & 63;
    int w    = gtid >> 6;
    int nw   = (gridDim.x * blockDim.x) >> 6;
    int cnt  = g_flagCnt;
    if (cnt > FLAG_CAP) cnt = FLAG_CAP;
    int is64 = g_is64;

    for (int f = w; f < cnt; f += nw) {
        int b = g_flags[f];
        unsigned int addr = is64 ? va32[2 * b] : va32[b];
        int k0 = lane * 2;
        double a0 = (double)b1[k0], a1 = (double)b1[k0 + 1];
        for (int bit = 0; bit < 31; bit++) {           // wave-uniform branch
            if ((addr >> bit) & 1u) {
                a0 += (double)W1[bit * 128 + k0];
                a1 += (double)W1[bit * 128 + k0 + 1];
            }
        }
        double h0 = 0.5 * a0 * (1.0 + erf(a0 * 0.7071067811865476));
        double h1 = 0.5 * a1 * (1.0 + erf(a1 * 0.7071067811865476));
        unsigned int packed = 0;
        for (int j = 0; j < 26; j++) {
            double p = h0 * (double)W2[k0 * 64 + j] + h1 * (double)W2[(k0 + 1) * 64 + j];
#pragma unroll
            for (int s = 32; s > 0; s >>= 1) p += __shfl_xor(p, s, 64);
            double logit = p + (double)b2[j];
            if (logit > 0.5) packed |= (1u << j);
        }
        if (lane == 0) out[b] = (int)packed;
    }
}

// ---------------- host launcher ----------------------------------------------
extern "C" void kernel_launch(void* const* d_in, const int* in_sizes, int n_in,
                              void* d_out, int out_size, void* d_ws, size_t ws_size,
                              hipStream_t stream) {
    const unsigned int* va32 = (const unsigned int*)d_in[0];
    const float* W1 = (const float*)d_in[1];
    const float* b1 = (const float*)d_in[2];
    const float* W2 = (const float*)d_in[3];
    const float* b2 = (const float*)d_in[4];
    int* out = (int*)d_out;
    int n = in_sizes[0];

    // W2/b2 -> __constant__ (D2D async copies; graph-capturable)
    void *pW2 = nullptr, *pB2 = nullptr;
    hipGetSymbolAddress(&pW2, HIP_SYMBOL(cW2));
    hipGetSymbolAddress(&pB2, HIP_SYMBOL(cB2));
    hipMemcpyAsync(pW2, (void*)W2, 128 * 64 * sizeof(float), hipMemcpyDeviceToDevice, stream);
    hipMemcpyAsync(pB2, (void*)b2, 64 * sizeof(float),       hipMemcpyDeviceToDevice, stream);

    int nchk = n / 2 < 65536 ? n / 2 : 65536;
    k_init<<<1, 256, 0, stream>>>(va32, nchk);
    k_build<<<(NROWS * 128 + 255) / 256, 256, 0, stream>>>(W1, b1);

    hipFuncSetAttribute((const void*)k_main, hipFuncAttributeMaxDynamicSharedMemorySize,
                        LUT_FLOATS * sizeof(float));

    int blocks = (n + 1023) / 1024;
    k_main<<<blocks, 1024, LUT_FLOATS * sizeof(float), stream>>>(va32, out, n);
    k_rescue<<<512, 256, 0, stream>>>(va32, W1, b1, W2, b2, out);
}